// Round 5
// baseline (992.222 us; speedup 1.0000x reference)
//
#include <hip/hip_runtime.h>
#include <hip/hip_cooperative_groups.h>
#include <limits.h>

namespace cg = cooperative_groups;

#define N_PART 262144
#define GRID_DIM 256
#define NUM_CELLS (GRID_DIM * GRID_DIM)
#define KSLOT 32
#define MAXNB 64
#define NBLK 1024
#define NTHR 256
#define SLOTS 4   // query tasks per cell; slot-strided particle loop

// ---------------- ws layout ----------------
// ws+256                           : table ((NUM_CELLS+1)*KSLOT ints)
// next 16B                         : params (3 u32, zeroed in phase 0):
//                                    [0]=max(~bits x) [1]=max(~bits y) [2]=max(bits h)
// next                             : counts ((NUM_CELLS+1) ints)
// Table slots >= count are never read (sort pads with INT_MAX, query bounds
// by counts), so the table is never cleared.

#define CE(a, b) { int lo = min(a, b), hi = max(a, b); a = lo; b = hi; }

__global__ __launch_bounds__(NTHR, 4)
void fused_kernel(const float* __restrict__ pos, const float* __restrict__ sup,
                  unsigned int* __restrict__ params, int* __restrict__ counts,
                  int* __restrict__ table, float* __restrict__ outN,
                  float* __restrict__ outC, float* __restrict__ outR) {
#pragma clang fp contract(off)
    cg::grid_group grid = cg::this_grid();
    const int tid  = blockIdx.x * NTHR + threadIdx.x;
    const int nthr = NBLK * NTHR;                 // 262144 == N_PART
    const int lane = threadIdx.x & 63;
    const float2* pos2 = (const float2*)pos;

    // ---- phase 0: zero counts + params (ws is poisoned each call) ----
    for (int c = tid; c <= NUM_CELLS; c += nthr) counts[c] = 0;
    if (tid < 3) params[tid] = 0u;
    grid.sync();

    // ---- phase 1: min(pos) / max(sup) reduce ----
    // min over non-negative floats == ~(max over ~bits)
    {
        unsigned int nx = 0u, ny = 0u, hh = 0u;
        for (int i = tid; i < N_PART; i += nthr) {
            float2 p = pos2[i];
            nx = max(nx, ~__float_as_uint(p.x));
            ny = max(ny, ~__float_as_uint(p.y));
            hh = max(hh, __float_as_uint(sup[i]));
        }
        for (int m = 32; m > 0; m >>= 1) {   // wave butterfly
            nx = max(nx, (unsigned int)__shfl_xor((int)nx, m));
            ny = max(ny, (unsigned int)__shfl_xor((int)ny, m));
            hh = max(hh, (unsigned int)__shfl_xor((int)hh, m));
        }
        if (lane == 0) {
            atomicMax(&params[0], nx);
            atomicMax(&params[1], ny);
            atomicMax(&params[2], hh);
        }
    }
    grid.sync();

    // ---- phase 2: bin particles into cells ----
    {
        float hmax  = __uint_as_float(params[2]);
        float qminx = __uint_as_float(~params[0]) - hmax;
        float qminy = __uint_as_float(~params[1]) - hmax;
        for (int i = tid; i < N_PART; i += nthr) {
            float2 p = pos2[i];
            int cx = (int)ceilf((p.x - qminx) / hmax);
            int cy = (int)ceilf((p.y - qminy) / hmax);
            cx = min(max(cx, 0), GRID_DIM - 1);
            cy = min(max(cy, 0), GRID_DIM - 1);
            int lin = cx + GRID_DIM * cy;
            int slot = atomicAdd(&counts[lin], 1);
            if (slot < KSLOT) table[lin * KSLOT + slot] = i;
            // Poisson(4): count>32 never happens for this data.
        }
    }
    grid.sync();

    // ---- phase 3: per-cell sort (restore ascending-index = stable argsort) ----
    for (int c = tid; c < NUM_CELLS; c += nthr) {
        int cnt = min(counts[c], KSLOT);
        if (cnt < 2) continue;
        int* row = table + (size_t)c * KSLOT;
        if (cnt <= 4) {              // ~74% of cells
            int4 a = ((int4*)row)[0];
            int v0 = a.x, v1 = a.y, v2 = a.z, v3 = a.w;
            if (cnt < 4) v3 = INT_MAX;
            if (cnt < 3) v2 = INT_MAX;
            CE(v0, v1); CE(v2, v3); CE(v0, v2); CE(v1, v3); CE(v1, v2);
            ((int4*)row)[0] = make_int4(v0, v1, v2, v3);
        } else if (cnt <= 8) {
            int4 a = ((int4*)row)[0];
            int4 b = ((int4*)row)[1];
            int v0 = a.x, v1 = a.y, v2 = a.z, v3 = a.w;
            int v4 = b.x, v5 = b.y, v6 = b.z, v7 = b.w;
            if (cnt < 8) v7 = INT_MAX;
            if (cnt < 7) v6 = INT_MAX;
            if (cnt < 6) v5 = INT_MAX;
            if (cnt < 5) v4 = INT_MAX;
            CE(v0, v1); CE(v2, v3); CE(v4, v5); CE(v6, v7);
            CE(v0, v2); CE(v1, v3); CE(v4, v6); CE(v5, v7);
            CE(v1, v2); CE(v5, v6);
            CE(v0, v4); CE(v1, v5); CE(v2, v6); CE(v3, v7);
            CE(v1, v4); CE(v3, v6);
            CE(v2, v4); CE(v3, v5);
            CE(v3, v4);
            ((int4*)row)[0] = make_int4(v0, v1, v2, v3);
            ((int4*)row)[1] = make_int4(v4, v5, v6, v7);
        } else {
            for (int a2 = 1; a2 < cnt; a2++) {
                int v = row[a2];
                int b2 = a2 - 1;
                while (b2 >= 0 && row[b2] > v) { row[b2 + 1] = row[b2]; b2--; }
                row[b2 + 1] = v;
            }
        }
    }
    grid.sync();

    // ---- phase 4: query. task = (cell, slot), slot in [0,4); wave handles
    // particles slot, slot+4, ... of its cell with candidates preloaded once.
    // Cell-major task order => adjacent waves share table/pos L1/L2 lines. ----
    {
        const int offs[9] = {-257, -1, 255, -256, 0, 256, -255, 1, 257};
        const unsigned long long lmask = (1ull << lane) - 1ull;
        int gwave = tid >> 6;
        int nwav  = nthr >> 6;
        for (int t = gwave; t < NUM_CELLS * SLOTS; t += nwav) {
            int cell = t / SLOTS;
            int slot = t - cell * SLOTS;
            int cnt = min(counts[cell], KSLOT);
            if (slot >= cnt) continue;
            int cum[10];
            cum[0] = 0;
            for (int o = 0; o < 9; o++) {
                int cc = cell + offs[o];
                cc = min(max(cc, 0), NUM_CELLS);
                cum[o + 1] = cum[o] + min(counts[cc], KSLOT);
            }
            int T = cum[9];
            int c4 = cum[4];   // center segment start; slot p == candidate c4+p
            if (T <= 64) {     // all cells in practice (Poisson(36))
                int j = 0; float qx = 0.0f, qy = 0.0f, hl = 0.0f;
                if (lane < T) {
                    int o = 0;
                    for (int m = 1; m <= 8; m++) o += (lane >= cum[m]);
                    int cc = cell + offs[o];
                    cc = min(max(cc, 0), NUM_CELLS);
                    j = table[cc * KSLOT + (lane - cum[o])];
                    float2 q = pos2[j];
                    qx = q.x; qy = q.y;
                    if (lane >= c4 && lane < c4 + cnt) hl = sup[j];
                }
                for (int p = slot; p < cnt; p += SLOTS) {
                    int   jp = __shfl(j,  c4 + p);
                    float px = __shfl(qx, c4 + p);
                    float py = __shfl(qy, c4 + p);
                    float h  = __shfl(hl, c4 + p);
                    float dx = qx - px;
                    float dy = qy - py;
                    float s  = dx * dx + dy * dy;  // contract(off): match XLA
                    float d  = sqrtf(s);
                    bool valid = (lane < T) && (d <= h);
                    unsigned long long bal = __ballot(valid);
                    int rank  = __popcll(bal & lmask);
                    int total = __popcll(bal);     // <= T <= 64
                    size_t base = (size_t)jp * MAXNB;
                    if (valid) {
                        outN[base + rank] = (float)j;
                        outR[base + rank] = d / h;
                    }
                    if (lane >= total) {
                        outN[base + lane] = -1.0f;
                        outR[base + lane] = 0.0f;
                    }
                    if (lane == 0) outC[jp] = (float)total;
                }
            } else {
                // rare slow path: chunked per-particle scan
                for (int p = slot; p < cnt; p += SLOTS) {
                    int jp = table[cell * KSLOT + p];
                    float2 pp = pos2[jp];
                    float h = sup[jp];
                    int total = 0;
                    size_t base = (size_t)jp * MAXNB;
                    for (int bb = 0; bb < T; bb += 64) {
                        int ll = bb + lane;
                        bool active = ll < T;
                        int j2 = 0;
                        float d = 0.0f;
                        if (active) {
                            int o = 0;
                            for (int m = 1; m <= 8; m++) o += (ll >= cum[m]);
                            int cc = cell + offs[o];
                            cc = min(max(cc, 0), NUM_CELLS);
                            j2 = table[cc * KSLOT + (ll - cum[o])];
                            float2 q = pos2[j2];
                            float dx = q.x - pp.x;
                            float dy = q.y - pp.y;
                            float s = dx * dx + dy * dy;
                            d = sqrtf(s);
                        }
                        bool valid = active && (d <= h);
                        unsigned long long bal = __ballot(valid);
                        int w = total + __popcll(bal & lmask);
                        if (valid && w < MAXNB) {
                            outN[base + w] = (float)j2;
                            outR[base + w] = d / h;
                        }
                        total += __popcll(bal);
                    }
                    if (lane >= min(total, MAXNB)) {
                        outN[base + lane] = -1.0f;
                        outR[base + lane] = 0.0f;
                    }
                    if (lane == 0) outC[jp] = (float)total;
                }
            }
        }
    }
}

extern "C" void kernel_launch(void* const* d_in, const int* in_sizes, int n_in,
                              void* d_out, int out_size, void* d_ws, size_t ws_size,
                              hipStream_t stream) {
    const float* pos = (const float*)d_in[0];
    const float* sup = (const float*)d_in[1];

    char* ws = (char*)d_ws;
    int* table = (int*)(ws + 256);
    unsigned int* params = (unsigned int*)(ws + 256 + (size_t)(NUM_CELLS + 1) * KSLOT * 4);
    int* counts = (int*)((char*)params + 16);

    float* out  = (float*)d_out;
    float* outN = out;                              // N*64 neighbor ids (as f32)
    float* outC = out + (size_t)N_PART * MAXNB;     // N counts
    float* outR = outC + N_PART;                    // N*64 radial

    void* args[8] = { (void*)&pos, (void*)&sup, (void*)&params, (void*)&counts,
                      (void*)&table, (void*)&outN, (void*)&outC, (void*)&outR };
    hipLaunchCooperativeKernel((void*)fused_kernel, dim3(NBLK), dim3(NTHR),
                               args, 0, stream);
}

// Round 6
// 343.110 us; speedup vs baseline: 2.8919x; 2.8919x over previous
//
#include <hip/hip_runtime.h>
#include <limits.h>

#define N_PART 262144
#define GRID_DIM 256
#define NUM_CELLS (GRID_DIM * GRID_DIM)
#define KSLOT 32
#define MAXNB 64
#define NPARTIAL 256

// ---------------- ws layout (nothing needs host-side init) ----------------
// ws + 0                       : partials (NPARTIAL * uint4)  [reduce writes all]
// ws + 4096                    : counts ((NUM_CELLS+1) ints)  [reduce zeroes]
// ws + 4096 + 262160           : table ((NUM_CELLS+1)*KSLOT ints) [never cleared:
//                                slots >= count are never read]

// min over non-negative floats == ~(max over ~bits of x)

__global__ __launch_bounds__(256)
void reduce_kernel(const float* __restrict__ pos, const float* __restrict__ sup,
                   uint4* __restrict__ partials, int* __restrict__ counts) {
    // side job: zero counts (no dependency; bin runs in a later dispatch)
    int tid = blockIdx.x * 256 + threadIdx.x;   // 65536 threads
    for (int c = tid; c <= NUM_CELLS; c += NPARTIAL * 256) counts[c] = 0;

    __shared__ unsigned int s_nx, s_ny, s_h;
    if (threadIdx.x == 0) { s_nx = 0u; s_ny = 0u; s_h = 0u; }
    __syncthreads();
    unsigned int nx = 0u, ny = 0u, hh = 0u;
    const float2* pos2 = (const float2*)pos;
    for (int i = tid; i < N_PART; i += NPARTIAL * 256) {
        float2 p = pos2[i];
        nx = max(nx, ~__float_as_uint(p.x));
        ny = max(ny, ~__float_as_uint(p.y));
        hh = max(hh, __float_as_uint(sup[i]));
    }
    atomicMax(&s_nx, nx);
    atomicMax(&s_ny, ny);
    atomicMax(&s_h, hh);
    __syncthreads();
    if (threadIdx.x == 0)
        partials[blockIdx.x] = make_uint4(s_nx, s_ny, s_h, 0u);
}

__global__ __launch_bounds__(256)
void bin_kernel(const float* __restrict__ pos,
                const uint4* __restrict__ partials,
                int* __restrict__ counts, int* __restrict__ table) {
    // finalize the 256 per-block partials once per block (L2-hot, ~4KB)
    __shared__ unsigned int s_par[3];
    if (threadIdx.x < 64) {
        unsigned int nx = 0u, ny = 0u, hh = 0u;
        for (int k = threadIdx.x; k < NPARTIAL; k += 64) {
            uint4 p = partials[k];
            nx = max(nx, p.x); ny = max(ny, p.y); hh = max(hh, p.z);
        }
        for (int m = 32; m > 0; m >>= 1) {
            nx = max(nx, (unsigned int)__shfl_xor((int)nx, m));
            ny = max(ny, (unsigned int)__shfl_xor((int)ny, m));
            hh = max(hh, (unsigned int)__shfl_xor((int)hh, m));
        }
        if (threadIdx.x == 0) { s_par[0] = nx; s_par[1] = ny; s_par[2] = hh; }
    }
    __syncthreads();
    float hmax  = __uint_as_float(s_par[2]);
    float qminx = __uint_as_float(~s_par[0]) - hmax;
    float qminy = __uint_as_float(~s_par[1]) - hmax;

    int i = blockIdx.x * 256 + threadIdx.x;
    if (i >= N_PART) return;
    float2 p = ((const float2*)pos)[i];
    int cx = (int)ceilf((p.x - qminx) / hmax);
    int cy = (int)ceilf((p.y - qminy) / hmax);
    cx = min(max(cx, 0), GRID_DIM - 1);
    cy = min(max(cy, 0), GRID_DIM - 1);
    int lin = cx + GRID_DIM * cy;
    int slot = atomicAdd(&counts[lin], 1);
    if (slot < KSLOT) table[lin * KSLOT + slot] = i;
    // Poisson(4): count>32 never happens for this data.
}

#define CE(a, b) { int lo = min(a, b), hi = max(a, b); a = lo; b = hi; }

__global__ __launch_bounds__(256)
void sort_kernel(const int* __restrict__ counts, int* __restrict__ table) {
    int c = blockIdx.x * 256 + threadIdx.x;
    if (c >= NUM_CELLS) return;
    int cnt = min(counts[c], KSLOT);
    if (cnt < 2) return;
    int* row = table + (size_t)c * KSLOT;
    if (cnt <= 4) {              // ~74% of cells: touch only 16B
        int4 a = ((int4*)row)[0];
        int v0 = a.x, v1 = a.y, v2 = a.z, v3 = a.w;
        if (cnt < 4) v3 = INT_MAX;
        if (cnt < 3) v2 = INT_MAX;
        CE(v0, v1); CE(v2, v3); CE(v0, v2); CE(v1, v3); CE(v1, v2);
        ((int4*)row)[0] = make_int4(v0, v1, v2, v3);
    } else if (cnt <= 8) {
        int4 a = ((int4*)row)[0];
        int4 b = ((int4*)row)[1];
        int v0 = a.x, v1 = a.y, v2 = a.z, v3 = a.w;
        int v4 = b.x, v5 = b.y, v6 = b.z, v7 = b.w;
        if (cnt < 8) v7 = INT_MAX;
        if (cnt < 7) v6 = INT_MAX;
        if (cnt < 6) v5 = INT_MAX;
        if (cnt < 5) v4 = INT_MAX;
        CE(v0, v1); CE(v2, v3); CE(v4, v5); CE(v6, v7);
        CE(v0, v2); CE(v1, v3); CE(v4, v6); CE(v5, v7);
        CE(v1, v2); CE(v5, v6);
        CE(v0, v4); CE(v1, v5); CE(v2, v6); CE(v3, v7);
        CE(v1, v4); CE(v3, v6);
        CE(v2, v4); CE(v3, v5);
        CE(v3, v4);
        ((int4*)row)[0] = make_int4(v0, v1, v2, v3);
        ((int4*)row)[1] = make_int4(v4, v5, v6, v7);
    } else {
        for (int a2 = 1; a2 < cnt; a2++) {
            int v = row[a2];
            int b2 = a2 - 1;
            while (b2 >= 0 && row[b2] > v) { row[b2 + 1] = row[b2]; b2--; }
            row[b2 + 1] = v;
        }
    }
}

// One BLOCK per cell; the block's 4 waves take slots 0-3 (particles slot,
// slot+4, ...). Full-size grid restores round-2 parallelism; cell-major
// order gives round-4 L2/L1 locality (the 4 waves' candidate gathers hit
// the same L1 lines). Direct rank-scattered stores: valid lanes write
// [rank], lanes >= total write filler at [lane] => every 256B output row is
// fully covered by one wave, no partial-line RMW.
__global__ __launch_bounds__(256)
void query_kernel(const float* __restrict__ pos, const float* __restrict__ sup,
                  const int* __restrict__ counts, const int* __restrict__ table,
                  float* __restrict__ outN, float* __restrict__ outC,
                  float* __restrict__ outR) {
#pragma clang fp contract(off)
    int wsl  = threadIdx.x >> 6;   // slot 0..3
    int lane = threadIdx.x & 63;
    // XCD-contiguous swizzle: each of 8 XCDs gets a contiguous cell band
    int b = blockIdx.x;
    int cell = (b & 7) * (NUM_CELLS / 8) + (b >> 3);
    int cnt = min(counts[cell], KSLOT);
    if (wsl >= cnt) return;        // wave-uniform exit

    const float2* pos2 = (const float2*)pos;
    const int offs[9] = {-257, -1, 255, -256, 0, 256, -255, 1, 257};
    int cum[10];
    cum[0] = 0;
    for (int o = 0; o < 9; o++) {
        int cc = cell + offs[o];
        cc = min(max(cc, 0), NUM_CELLS);
        cum[o + 1] = cum[o] + min(counts[cc], KSLOT);
    }
    int T = cum[9];
    int c4 = cum[4];   // center segment start; slot p == candidate c4+p
    unsigned long long lmask = (1ull << lane) - 1ull;

    if (T <= 64) {     // all cells in practice (Poisson(36))
        // ---- candidate preload (per wave; L1-shared across the block) ----
        int j = 0; float qx = 0.0f, qy = 0.0f, hl = 0.0f;
        if (lane < T) {
            int o = 0;
            for (int m = 1; m <= 8; m++) o += (lane >= cum[m]);
            int cc = cell + offs[o];
            cc = min(max(cc, 0), NUM_CELLS);
            j = table[cc * KSLOT + (lane - cum[o])];
            float2 q = pos2[j];
            qx = q.x; qy = q.y;
            if (lane >= c4 && lane < c4 + cnt) hl = sup[j];
        }
        for (int p = wsl; p < cnt; p += 4) {
            int   jp = __shfl(j,  c4 + p);
            float px = __shfl(qx, c4 + p);
            float py = __shfl(qy, c4 + p);
            float h  = __shfl(hl, c4 + p);
            float dx = qx - px;
            float dy = qy - py;
            float s  = dx * dx + dy * dy;   // contract(off): match XLA exactly
            float d  = sqrtf(s);
            bool valid = (lane < T) && (d <= h);
            unsigned long long bal = __ballot(valid);
            int rank  = __popcll(bal & lmask);
            int total = __popcll(bal);      // <= T <= 64
            size_t base = (size_t)jp * MAXNB;
            if (valid) {
                outN[base + rank] = (float)j;
                outR[base + rank] = d / h;
            }
            if (lane >= total) {
                outN[base + lane] = -1.0f;
                outR[base + lane] = 0.0f;
            }
            if (lane == 0) outC[jp] = (float)total;
        }
    } else {
        // ---- rare slow path: chunked per-particle scan ----
        for (int p = wsl; p < cnt; p += 4) {
            int jp = table[cell * KSLOT + p];
            float2 pp = pos2[jp];
            float h = sup[jp];
            int total = 0;
            size_t base = (size_t)jp * MAXNB;
            for (int bb = 0; bb < T; bb += 64) {
                int ll = bb + lane;
                bool active = ll < T;
                int j2 = 0;
                float d = 0.0f;
                if (active) {
                    int o = 0;
                    for (int m = 1; m <= 8; m++) o += (ll >= cum[m]);
                    int cc = cell + offs[o];
                    cc = min(max(cc, 0), NUM_CELLS);
                    j2 = table[cc * KSLOT + (ll - cum[o])];
                    float2 q = pos2[j2];
                    float dx = q.x - pp.x;
                    float dy = q.y - pp.y;
                    float s = dx * dx + dy * dy;
                    d = sqrtf(s);
                }
                bool valid = active && (d <= h);
                unsigned long long bal = __ballot(valid);
                int w = total + __popcll(bal & lmask);
                if (valid && w < MAXNB) {
                    outN[base + w] = (float)j2;
                    outR[base + w] = d / h;
                }
                total += __popcll(bal);
            }
            if (lane >= min(total, MAXNB)) {
                outN[base + lane] = -1.0f;
                outR[base + lane] = 0.0f;
            }
            if (lane == 0) outC[jp] = (float)total;
        }
    }
}

extern "C" void kernel_launch(void* const* d_in, const int* in_sizes, int n_in,
                              void* d_out, int out_size, void* d_ws, size_t ws_size,
                              hipStream_t stream) {
    const float* pos = (const float*)d_in[0];
    const float* sup = (const float*)d_in[1];

    char* ws = (char*)d_ws;
    uint4* partials = (uint4*)ws;
    int* counts = (int*)(ws + 4096);
    int* table  = (int*)(ws + 4096 + 262160);

    float* out  = (float*)d_out;
    float* outN = out;                              // N*64 neighbor ids (as f32)
    float* outC = out + (size_t)N_PART * MAXNB;     // N counts
    float* outR = outC + N_PART;                    // N*64 radial

    reduce_kernel<<<NPARTIAL, 256, 0, stream>>>(pos, sup, partials, counts);
    bin_kernel<<<N_PART / 256, 256, 0, stream>>>(pos, partials, counts, table);
    sort_kernel<<<NUM_CELLS / 256, 256, 0, stream>>>(counts, table);
    query_kernel<<<NUM_CELLS, 256, 0, stream>>>(pos, sup, counts, table,
                                                outN, outC, outR);
}